// Round 2
// baseline (1824.690 us; speedup 1.0000x reference)
//
#include <hip/hip_runtime.h>
#include <math.h>

// Problem constants (fixed by the reference)
constexpr int B_ = 32, T_ = 2048, E_ = 512, F_ = 512, KW = 7, H_ = 8;
constexpr float EPS_ = 1e-5f;

typedef unsigned short bfu;   // raw bf16 bits (internal workspace format)
typedef __attribute__((ext_vector_type(8))) unsigned short ushort8v;
typedef __attribute__((ext_vector_type(8))) short short8v;   // MFMA A/B frag (8 bf16)
typedef __attribute__((ext_vector_type(4))) short short4v;
typedef __attribute__((ext_vector_type(4))) float f32x4;     // MFMA C/D frag 16x16
typedef __attribute__((ext_vector_type(16))) float f32x16;   // MFMA C/D frag 32x32
typedef const __attribute__((address_space(1))) void* gp1_t;
typedef __attribute__((address_space(3))) void* lp3_t;

__device__ __forceinline__ float b2f(bfu u) {
    return __uint_as_float(((unsigned)u) << 16);
}
__device__ __forceinline__ bfu f2b(float f) {
    unsigned i = __float_as_uint(f);
    i += 0x7fffu + ((i >> 16) & 1u);   // round-to-nearest-even
    return (bfu)(i >> 16);
}

template <typename T> __device__ __forceinline__ void stv(T* p, size_t i, float v);
template <> __device__ __forceinline__ void stv<bfu>(bfu* p, size_t i, float v)   { p[i] = f2b(v); }
template <> __device__ __forceinline__ void stv<float>(float* p, size_t i, float v) { p[i] = v; }

// ---------------------------------------------------------------------------
__global__ void zero_kernel(float* p, int n) {
    int i = blockIdx.x * 256 + threadIdx.x;
    if (i < n) p[i] = 0.f;
}

// ---------------------------------------------------------------------------
// One-shot prep: 7 weight matrices fp32->bf16 + pe table (pe[b,e], 32x512).
__global__ __launch_bounds__(256) void prep(const float* __restrict__ w0, const float* __restrict__ w1,
                                            const float* __restrict__ w2, const float* __restrict__ w3,
                                            const float* __restrict__ w4, const float* __restrict__ w5,
                                            const float* __restrict__ w6,
                                            bfu* __restrict__ wb, float* __restrict__ pe) {
    int idx = blockIdx.x * 256 + threadIdx.x;
    if (idx < 7 * 65536) {
        int w = idx >> 16, off = (idx & 65535) * 4;
        const float* src = w0;
        switch (w) {
            case 1: src = w1; break; case 2: src = w2; break; case 3: src = w3; break;
            case 4: src = w4; break; case 5: src = w5; break; case 6: src = w6; break;
            default: break;
        }
        float4 v = *(const float4*)(src + off);
        ushort4 u = { f2b(v.x), f2b(v.y), f2b(v.z), f2b(v.w) };
        *(ushort4*)(wb + (size_t)w * 262144 + off) = u;
    } else {
        int i = (idx - 7 * 65536) * 4;
        if (i < 16384) {
            #pragma unroll
            for (int e4 = 0; e4 < 4; e4++) {
                int ii = i + e4;
                int b = ii >> 9, e = ii & 511;
                float div = expf(-(float)(e & ~1) * (logf(10000.0f) / (float)E_));
                float ang = (float)b * div;
                pe[ii] = (e & 1) ? cosf(ang) : sinf(ang);
            }
        }
    }
}

// ---------------------------------------------------------------------------
// x (B,T,E) fp32 + pe[b,e] -> bf16 (B,T,E), with fused per-b LN stats.
// Grid 8192 blocks x 4096 elems; each block lies within one b.
__global__ __launch_bounds__(256) void add_pe(const float* __restrict__ x,
                                              const float* __restrict__ pe,
                                              bfu* __restrict__ out,
                                              float* __restrict__ stats) {
    size_t base = (size_t)blockIdx.x * 4096;
    int b = (int)(base >> 20);                 // T_*E_ = 2^20 elems per batch
    float sum = 0.f, sq = 0.f;
    #pragma unroll
    for (int u = 0; u < 4; u++) {
        size_t i = base + u * 1024 + threadIdx.x * 4;
        int e = (int)(i & 511);
        float4 xv = *(const float4*)(x + i);
        float4 pv = *(const float4*)(pe + (b << 9) + e);
        float a0 = xv.x + pv.x, a1 = xv.y + pv.y, a2 = xv.z + pv.z, a3 = xv.w + pv.w;
        ushort4 o = { f2b(a0), f2b(a1), f2b(a2), f2b(a3) };
        *(ushort4*)(out + i) = o;
        sum += a0 + a1 + a2 + a3;
        sq  += a0 * a0 + a1 * a1 + a2 * a2 + a3 * a3;
    }
    #pragma unroll
    for (int off = 32; off > 0; off >>= 1) {
        sum += __shfl_down(sum, off, 64);
        sq  += __shfl_down(sq,  off, 64);
    }
    __shared__ float ss[8];
    int lane = threadIdx.x & 63, wv = threadIdx.x >> 6;
    if (lane == 0) { ss[wv] = sum; ss[4 + wv] = sq; }
    __syncthreads();
    if (threadIdx.x == 0) {
        atomicAdd(&stats[2 * b],     ss[0] + ss[1] + ss[2] + ss[3]);
        atomicAdd(&stats[2 * b + 1], ss[4] + ss[5] + ss[6] + ss[7]);
    }
}

__device__ __forceinline__ float ln_rstd(float sumsq, float mu, float invL) {
    float var = fmaxf(sumsq * invL - mu * mu, 0.f);
    return rsqrtf(var + EPS_);
}

// ---------------------------------------------------------------------------
// Depthwise conv in NHWC (B,T,F), K=7 pad 3, LN fused (per-b stats).
__global__ __launch_bounds__(256) void dwconv_nhwc(const bfu* __restrict__ x,
                                                   const float* __restrict__ stats,
                                                   const float* __restrict__ w,
                                                   const float* __restrict__ bias,
                                                   bfu* __restrict__ out) {
    __shared__ float ws[64 * 57];   // [f-chunk][(f&7)*7 + dt]
    int tid = threadIdx.x;
    int b = blockIdx.z;
    for (int i = tid; i < F_ * KW; i += 256) {
        int f = i / KW, dt = i - f * KW;
        ws[(f >> 3) * 57 + (f & 7) * 7 + dt] = w[i];
    }
    __syncthreads();
    const float invL = 1.0f / (float)(F_ * T_);
    float mu   = stats[2 * b] * invL;
    float rstd = ln_rstd(stats[2 * b + 1], mu, invL);
    int f0 = (tid & 63) * 8;
    int t  = blockIdx.x * 4 + (tid >> 6);
    const bfu* xb = x + (size_t)b * T_ * F_;
    const float* wc_ = &ws[(tid & 63) * 57];
    float acc[8];
    #pragma unroll
    for (int j = 0; j < 8; j++) acc[j] = bias[f0 + j];
    #pragma unroll
    for (int dt = 0; dt < KW; dt++) {
        int tt = t + dt - KW / 2;
        if (tt >= 0 && tt < T_) {
            ushort8v v = *(const ushort8v*)(xb + (size_t)tt * F_ + f0);
            #pragma unroll
            for (int j = 0; j < 8; j++)
                acc[j] += wc_[j * 7 + dt] * ((b2f(v[j]) - mu) * rstd);
        }
    }
    ushort8v o;
    #pragma unroll
    for (int j = 0; j < 8; j++) o[j] = f2b(acc[j]);
    *(ushort8v*)(out + ((size_t)b * T_ + t) * F_ + f0) = o;
}

// ---------------------------------------------------------------------------
// MFMA NT GEMM (m97 structure) with optional fused LN-stat reduction.
// GMODE 0: none. GMODE 1: one group per block, g = r0>>11 (per-b, rows b*2048+t).
// GMODE 2: group per 32 rows, g = r>>5 (per-t, rows t*32+b).
template <typename OutT, int GMODE>
__global__ __launch_bounds__(256) void gemm_mfma(const bfu* __restrict__ A,
                                                 const bfu* __restrict__ Wb,
                                                 const float* __restrict__ bias,
                                                 const bfu* res, OutT* out,
                                                 int out_transpose, float* stats) {
    constexpr int Kd = 512;
    __shared__ bfu As[128 * 32];   // 8 KB, row stride 64 B
    __shared__ bfu Bs[128 * 32];
    int id  = blockIdx.x;
    int swz = (id & 7) * 256 + (id >> 3);
    int m0 = (swz & 3) * 128;
    int r0 = (swz >> 2) * 128;
    int tid  = threadIdx.x;
    int wave = tid >> 6, lane = tid & 63;
    int wr = (wave >> 1) * 64, wc = (wave & 1) * 64;
    int lg = lane >> 4,  lr = lane & 15;

    const char* Ab = (const char*)A  + (size_t)r0 * 1024;
    const char* Bb = (const char*)Wb + (size_t)m0 * 1024;
    char* AsB = (char*)As;
    char* BsB = (char*)Bs;
    int rS = (wave << 4) + (lane >> 2);
    int kb = (lane & 3) << 4;
    int ldsoff = wave << 10;

    f32x4 acc[4][4];
    #pragma unroll
    for (int mi = 0; mi < 4; mi++)
        #pragma unroll
        for (int ni = 0; ni < 4; ni++)
            acc[mi][ni] = (f32x4){0.f, 0.f, 0.f, 0.f};

    const bfu* ApL = As + (wr + lr) * 32 + lg * 8;
    const bfu* BpL = Bs + (wc + lr) * 32 + lg * 8;

    for (int k0 = 0; k0 < Kd; k0 += 32) {
        size_t koff = (size_t)(k0 << 1);
        const char* a0 = Ab + (size_t)rS * 1024 + koff + kb;
        const char* b0 = Bb + (size_t)rS * 1024 + koff + kb;
        __builtin_amdgcn_global_load_lds((gp1_t)a0,           (lp3_t)(AsB + ldsoff),        16, 0, 0);
        __builtin_amdgcn_global_load_lds((gp1_t)(a0 + 65536), (lp3_t)(AsB + ldsoff + 4096), 16, 0, 0);
        __builtin_amdgcn_global_load_lds((gp1_t)b0,           (lp3_t)(BsB + ldsoff),        16, 0, 0);
        __builtin_amdgcn_global_load_lds((gp1_t)(b0 + 65536), (lp3_t)(BsB + ldsoff + 4096), 16, 0, 0);
        __syncthreads();
        short8v a[4], bb[4];
        #pragma unroll
        for (int mi = 0; mi < 4; mi++) a[mi]  = *(const short8v*)(ApL + mi * 512);
        #pragma unroll
        for (int ni = 0; ni < 4; ni++) bb[ni] = *(const short8v*)(BpL + ni * 512);
        #pragma unroll
        for (int mi = 0; mi < 4; mi++)
            #pragma unroll
            for (int ni = 0; ni < 4; ni++)
                acc[mi][ni] = __builtin_amdgcn_mfma_f32_16x16x32_bf16(a[mi], bb[ni], acc[mi][ni], 0, 0, 0);
        __syncthreads();
    }

    float sAcc0 = 0.f, sAcc1 = 0.f, qAcc0 = 0.f, qAcc1 = 0.f;
    #pragma unroll
    for (int ni = 0; ni < 4; ni++) {
        int m = m0 + wc + ni * 16 + lr;
        float bv = bias[m];
        #pragma unroll
        for (int mi = 0; mi < 4; mi++) {
            #pragma unroll
            for (int j = 0; j < 4; j++) {
                int r = r0 + wr + mi * 16 + lg * 4 + j;
                float v = acc[mi][ni][j] + bv;
                if (res) v += b2f(res[(size_t)r * 512 + m]);
                if (GMODE) {
                    if (mi < 2) { sAcc0 += v; qAcc0 += v * v; }
                    else        { sAcc1 += v; qAcc1 += v * v; }
                }
                if (!out_transpose) {
                    stv(out, (size_t)r * 512 + m, v);
                } else {
                    int t = r >> 5, bb2 = r & 31;
                    stv(out, ((size_t)bb2 * T_ + t) * 512 + m, v);
                }
            }
        }
    }
    if (GMODE == 1) {
        float s = sAcc0 + sAcc1, q = qAcc0 + qAcc1;
        #pragma unroll
        for (int off = 32; off > 0; off >>= 1) {
            s += __shfl_down(s, off, 64);
            q += __shfl_down(q, off, 64);
        }
        if (lane == 0) {
            int g = r0 >> 11;
            atomicAdd(&stats[2 * g], s);
            atomicAdd(&stats[2 * g + 1], q);
        }
    } else if (GMODE == 2) {
        #pragma unroll
        for (int off = 32; off > 0; off >>= 1) {
            sAcc0 += __shfl_down(sAcc0, off, 64); qAcc0 += __shfl_down(qAcc0, off, 64);
            sAcc1 += __shfl_down(sAcc1, off, 64); qAcc1 += __shfl_down(qAcc1, off, 64);
        }
        if (lane == 0) {
            int g0 = (r0 >> 5) + (wr >> 5);   // wave's first 32-row group
            atomicAdd(&stats[2 * g0],     sAcc0);
            atomicAdd(&stats[2 * g0 + 1], qAcc0);
            atomicAdd(&stats[2 * g0 + 2], sAcc1);
            atomicAdd(&stats[2 * g0 + 3], qAcc1);
        }
    }
}

// ---------------------------------------------------------------------------
// (B,T,F) -> (T,B,F): xa = raw copy, yln = LN-applied (per-b stats).
__global__ __launch_bounds__(256) void bt2tb_ln(const bfu* __restrict__ x,
                                                const float* __restrict__ stats,
                                                bfu* __restrict__ xa,
                                                bfu* __restrict__ yln) {
    size_t i = ((size_t)blockIdx.x * 256 + threadIdx.x) * 8;
    int f = (int)(i & 511);
    size_t bt = i >> 9;
    int t = (int)(bt & 2047);
    int b = (int)(bt >> 11);
    const float invL = 1.0f / (float)(F_ * T_);
    float mu   = stats[2 * b] * invL;
    float rstd = ln_rstd(stats[2 * b + 1], mu, invL);
    ushort8v v = *(const ushort8v*)(x + i);
    size_t dst = (((size_t)t * B_ + b) << 9) + f;
    *(ushort8v*)(xa + dst) = v;
    ushort8v o;
    #pragma unroll
    for (int j = 0; j < 8; j++) o[j] = f2b((b2f(v[j]) - mu) * rstd);
    *(ushort8v*)(yln + dst) = o;
}

// LN apply over contiguous groups of (1<<shift) elems.
__global__ __launch_bounds__(256) void ln_apply(const bfu* __restrict__ x,
                                                const float* __restrict__ stats,
                                                bfu* __restrict__ out,
                                                float invL, int shift) {
    size_t i = ((size_t)blockIdx.x * 256 + threadIdx.x) * 8;
    int g = (int)(i >> shift);
    float mu   = stats[2 * g] * invL;
    float rstd = ln_rstd(stats[2 * g + 1], mu, invL);
    ushort8v v = *(const ushort8v*)(x + i);
    ushort8v o;
    #pragma unroll
    for (int j = 0; j < 8; j++) o[j] = f2b((b2f(v[j]) - mu) * rstd);
    *(ushort8v*)(out + i) = o;
}

// ---------------------------------------------------------------------------
// MFMA attention over the batch axis. One wave per (t,h); 4 waves/block.
// S^T[c][b] = mfma(K, Q): swapped operands put each b-column's scores (over c)
// in-lane -> softmax = 16 reg ops + one shfl_xor(32). A/B fragments use the
// IDENTICAL k-slot mapping (kappa(h,j)) so any internal k permutation cancels.
// PV: A = packed P regs (C/D layout c = (r&3)+8*(r>>2)+4*lh, m101-verified),
// B = V^T from padded LDS read with the SAME kappa.
__global__ __launch_bounds__(256) void attention_mfma(const bfu* __restrict__ Q,
                                                      const bfu* __restrict__ K,
                                                      const bfu* __restrict__ V,
                                                      bfu* __restrict__ O) {
    __shared__ bfu vt[4][64 * 36];   // per-wave V^T [d][c], padded stride 36
    int tid = threadIdx.x;
    int wave = tid >> 6, lane = tid & 63;
    int wid = blockIdx.x * 4 + wave;
    int t = wid >> 3, h = wid & 7;
    int lh = lane >> 5, lm = lane & 31;
    size_t base = (size_t)t * (B_ * F_) + (size_t)h * 64;

    // Q/K fragments straight from global: lane holds row lm, k = s*16 + lh*8 + j
    short8v qf[4], kf[4];
    const bfu* qrow = Q + base + (size_t)lm * F_ + lh * 8;
    const bfu* krow = K + base + (size_t)lm * F_ + lh * 8;
    #pragma unroll
    for (int s = 0; s < 4; s++) {
        qf[s] = *(const short8v*)(qrow + s * 16);
        kf[s] = *(const short8v*)(krow + s * 16);
    }
    // stage V^T: lane handles c = lane>>1, d half = (lane&1)*32
    bfu* vt_w = vt[wave];
    {
        int c = lane >> 1, d0 = (lane & 1) * 32;
        const bfu* vrow = V + base + (size_t)c * F_ + d0;
        #pragma unroll
        for (int j = 0; j < 4; j++) {
            ushort8v vv = *(const ushort8v*)(vrow + j * 8);
            #pragma unroll
            for (int e = 0; e < 8; e++)
                vt_w[(d0 + j * 8 + e) * 36 + c] = vv[e];
        }
    }
    // S^T = K Q^T  (rows c via reg pattern, col b = lm)
    f32x16 st;
    #pragma unroll
    for (int r = 0; r < 16; r++) st[r] = 0.f;
    #pragma unroll
    for (int s = 0; s < 4; s++)
        st = __builtin_amdgcn_mfma_f32_32x32x16_bf16(kf[s], qf[s], st, 0, 0, 0);

    // softmax over c: 16 in-lane + exchange with lane^32
    float p[16];
    float mx = -1e30f;
    #pragma unroll
    for (int r = 0; r < 16; r++) { p[r] = st[r] * 0.125f; mx = fmaxf(mx, p[r]); }
    mx = fmaxf(mx, __shfl_xor(mx, 32, 64));
    float sum = 0.f;
    #pragma unroll
    for (int r = 0; r < 16; r++) { p[r] = expf(p[r] - mx); sum += p[r]; }
    sum += __shfl_xor(sum, 32, 64);
    float inv = 1.0f / sum;
    short8v pa[2];   // kappa(h,j): c = kh*16 + (j&3) + 8*(j>>2) + 4*lh  == reg order
    #pragma unroll
    for (int j = 0; j < 8; j++) {
        pa[0][j] = (short)f2b(p[j] * inv);
        pa[1][j] = (short)f2b(p[8 + j] * inv);
    }
    // O[b][d] = P V : A = pa (m=b=lm), B = V^T rows d = dt*32+lm, same kappa
    f32x16 oacc[2];
    #pragma unroll
    for (int dt = 0; dt < 2; dt++)
        #pragma unroll
        for (int r = 0; r < 16; r++) oacc[dt][r] = 0.f;
    #pragma unroll
    for (int dt = 0; dt < 2; dt++) {
        const bfu* vr = vt_w + (dt * 32 + lm) * 36 + lh * 4;
        #pragma unroll
        for (int kh = 0; kh < 2; kh++) {
            short4v b0 = *(const short4v*)(vr + kh * 16);
            short4v b1 = *(const short4v*)(vr + kh * 16 + 8);
            short8v bf;
            #pragma unroll
            for (int e = 0; e < 4; e++) { bf[e] = b0[e]; bf[4 + e] = b1[e]; }
            oacc[dt] = __builtin_amdgcn_mfma_f32_32x32x16_bf16(pa[kh], bf, oacc[dt], 0, 0, 0);
        }
    }
    // store: col d = dt*32+lm, row b = (r&3)+8*(r>>2)+4*lh
    bfu* orow = O + base + lm;
    #pragma unroll
    for (int dt = 0; dt < 2; dt++)
        #pragma unroll
        for (int r = 0; r < 16; r++) {
            int b = (r & 3) + 8 * (r >> 2) + 4 * lh;
            orow[(size_t)b * F_ + dt * 32] = f2b(oacc[dt][r]);
        }
}

// ---------------------------------------------------------------------------
extern "C" void kernel_launch(void* const* d_in, const int* in_sizes, int n_in,
                              void* d_out, int out_size, void* d_ws, size_t ws_size,
                              hipStream_t stream) {
    const float* x     = (const float*)d_in[0];
    const float* dw1_w = (const float*)d_in[1];
    const float* dw1_b = (const float*)d_in[2];
    const float* pw1_w = (const float*)d_in[3];
    const float* pw1_b = (const float*)d_in[4];
    const float* dw2_w = (const float*)d_in[5];
    const float* dw2_b = (const float*)d_in[6];
    const float* pw2_w = (const float*)d_in[7];
    const float* pw2_b = (const float*)d_in[8];
    const float* wq = (const float*)d_in[9];   const float* bq = (const float*)d_in[10];
    const float* wk = (const float*)d_in[11];  const float* bk = (const float*)d_in[12];
    const float* wv = (const float*)d_in[13];  const float* bv = (const float*)d_in[14];
    const float* wp = (const float*)d_in[15];  const float* bp = (const float*)d_in[16];
    const float* ffw = (const float*)d_in[17]; const float* ffb = (const float*)d_in[18];
    float* out = (float*)d_out;

    const size_t SZ = (size_t)B_ * F_ * T_;   // 33,554,432 elems (64 MB bf16)
    const size_t WN = (size_t)F_ * F_;

    // Workspace: [stats 32KB][pe 64KB][7 bf16 weights 3.5MB] ... big bufs @ +4MB
    float* stats = (float*)d_ws;              // 8192 fp32 total stat space
    float* stA = stats;                       // add_pe   (per-b, 64 used)
    float* st1 = stats + 128;                 // gemm pw1 (per-b)
    float* st2 = stats + 256;                 // gemm pw2 it0
    float* st3 = stats + 384;                 // gemm pw2 it1
    float* st4 = stats + 512;                 // gemm pw2 it2
    float* stT = stats + 1024;                // gemm wp  (per-t, 4096 used)
    float* peTab = stats + 8192;              // 16384 fp32
    bfu*   wBuf  = (bfu*)(peTab + 16384);
    bfu* wb_pw1 = wBuf + 0 * WN;
    bfu* wb_pw2 = wBuf + 1 * WN;
    bfu* wb_q   = wBuf + 2 * WN;
    bfu* wb_k   = wBuf + 3 * WN;
    bfu* wb_v   = wBuf + 4 * WN;
    bfu* wb_p   = wBuf + 5 * WN;
    bfu* wb_ff  = wBuf + 6 * WN;
    bfu* bufX = (bfu*)d_ws + (1 << 21);       // +4 MB: act (B,T,F); later Q
    bfu* bufC = bufX + SZ;                    // dwconv scratch; later xa (T,B,F)
    bfu* bufY = bufC + SZ;                    // yln (T,B,F); later attn O
    bfu* bufK = bufY + SZ;
    bfu* bufV = bufK + SZ;

    zero_kernel<<<32, 256, 0, stream>>>(stats, 8192);
    prep<<<1808, 256, 0, stream>>>(pw1_w, pw2_w, wq, wk, wv, wp, ffw, wBuf, peTab);
    add_pe<<<8192, 256, 0, stream>>>(x, peTab, bufX, stA);

    // conv1: x = pw1(dw1(ln(x0)))   [all in (B,T,F)]
    dwconv_nhwc<<<dim3(T_ / 4, 1, B_), 256, 0, stream>>>(bufX, stA, dw1_w, dw1_b, bufC);
    gemm_mfma<bfu, 1><<<2048, 256, 0, stream>>>(bufC, wb_pw1, pw1_b, nullptr, bufX, 0, st1);

    // conv loop (shared dw2/pw2 weights), residual + stats fused into gemm
    float* sts[3] = { st2, st3, st4 };
    for (int it = 0; it < 3; ++it) {
        float* sin_ = (it == 0) ? st1 : sts[it - 1];
        dwconv_nhwc<<<dim3(T_ / 4, 1, B_), 256, 0, stream>>>(bufX, sin_, dw2_w, dw2_b, bufC);
        gemm_mfma<bfu, 1><<<2048, 256, 0, stream>>>(bufC, wb_pw2, pw2_b, bufX, bufX, 0, sts[it]);
    }

    // to (T,B,F): xa = x (bufC), yln = ln(x) (bufY)
    bt2tb_ln<<<16384, 256, 0, stream>>>(bufX, st4, bufC, bufY);

    // QKV projections (bufX dead -> reuse for Q); rows r = (t,b)
    gemm_mfma<bfu, 0><<<2048, 256, 0, stream>>>(bufY, wb_q, bq, nullptr, bufX, 0, nullptr);
    gemm_mfma<bfu, 0><<<2048, 256, 0, stream>>>(bufY, wb_k, bk, nullptr, bufK, 0, nullptr);
    gemm_mfma<bfu, 0><<<2048, 256, 0, stream>>>(bufY, wb_v, bv, nullptr, bufV, 0, nullptr);

    // attention across batch axis (yln dead -> bufY holds O)
    attention_mfma<<<4096, 256, 0, stream>>>(bufX, bufK, bufV, bufY);

    // output projection + residual (xa in bufC) + per-t stats: xnew -> bufK
    gemm_mfma<bfu, 2><<<2048, 256, 0, stream>>>(bufY, wb_p, bp, bufC, bufK, 0, stT);

    // final LN per t over (B,F) = 16384 contiguous elems per group
    ln_apply<<<16384, 256, 0, stream>>>(bufK, stT, bufX, 1.0f / (float)(B_ * F_), 14);

    // FF gemm: A = ln(xnew), residual = xnew, fp32 (B,T,F) transposed output
    gemm_mfma<float, 0><<<2048, 256, 0, stream>>>(bufX, wb_ff, ffb, bufK, out, 1, nullptr);
}

// Round 3
// 1600.133 us; speedup vs baseline: 1.1403x; 1.1403x over previous
//
#include <hip/hip_runtime.h>
#include <math.h>

// Problem constants (fixed by the reference)
constexpr int B_ = 32, T_ = 2048, E_ = 512, F_ = 512, KW = 7, H_ = 8;
constexpr float EPS_ = 1e-5f;

typedef unsigned short bfu;   // raw bf16 bits (internal workspace format)
typedef __attribute__((ext_vector_type(8))) unsigned short ushort8v;
typedef __attribute__((ext_vector_type(8))) short short8v;   // MFMA A/B frag (8 bf16)
typedef __attribute__((ext_vector_type(4))) short short4v;
typedef __attribute__((ext_vector_type(4))) float f32x4;     // MFMA C/D frag 16x16
typedef __attribute__((ext_vector_type(16))) float f32x16;   // MFMA C/D frag 32x32
typedef const __attribute__((address_space(1))) void* gp1_t;
typedef __attribute__((address_space(3))) void* lp3_t;

__device__ __forceinline__ float b2f(bfu u) {
    return __uint_as_float(((unsigned)u) << 16);
}
__device__ __forceinline__ bfu f2b(float f) {
    unsigned i = __float_as_uint(f);
    i += 0x7fffu + ((i >> 16) & 1u);   // round-to-nearest-even
    return (bfu)(i >> 16);
}

// 4-wide packed store (8B for bf16, 16B for fp32)
template <typename T> __device__ __forceinline__ void st4(T* p, size_t i, float a, float b, float c, float d);
template <> __device__ __forceinline__ void st4<bfu>(bfu* p, size_t i, float a, float b, float c, float d) {
    ushort4 u = { f2b(a), f2b(b), f2b(c), f2b(d) };
    *(ushort4*)(p + i) = u;
}
template <> __device__ __forceinline__ void st4<float>(float* p, size_t i, float a, float b, float c, float d) {
    float4 u = { a, b, c, d };
    *(float4*)(p + i) = u;
}

// ---------------------------------------------------------------------------
__global__ void zero_kernel(float* p, int n) {
    int i = blockIdx.x * 256 + threadIdx.x;
    if (i < n) p[i] = 0.f;
}

// ---------------------------------------------------------------------------
// One-shot prep: 7 weight matrices fp32->bf16 + pe table (pe[b,e], 32x512).
__global__ __launch_bounds__(256) void prep(const float* __restrict__ w0, const float* __restrict__ w1,
                                            const float* __restrict__ w2, const float* __restrict__ w3,
                                            const float* __restrict__ w4, const float* __restrict__ w5,
                                            const float* __restrict__ w6,
                                            bfu* __restrict__ wb, float* __restrict__ pe) {
    int idx = blockIdx.x * 256 + threadIdx.x;
    if (idx < 7 * 65536) {
        int w = idx >> 16, off = (idx & 65535) * 4;
        const float* src = w0;
        switch (w) {
            case 1: src = w1; break; case 2: src = w2; break; case 3: src = w3; break;
            case 4: src = w4; break; case 5: src = w5; break; case 6: src = w6; break;
            default: break;
        }
        float4 v = *(const float4*)(src + off);
        ushort4 u = { f2b(v.x), f2b(v.y), f2b(v.z), f2b(v.w) };
        *(ushort4*)(wb + (size_t)w * 262144 + off) = u;
    } else {
        int i = (idx - 7 * 65536) * 4;
        if (i < 16384) {
            #pragma unroll
            for (int e4 = 0; e4 < 4; e4++) {
                int ii = i + e4;
                int b = ii >> 9, e = ii & 511;
                float div = expf(-(float)(e & ~1) * (logf(10000.0f) / (float)E_));
                float ang = (float)b * div;
                pe[ii] = (e & 1) ? cosf(ang) : sinf(ang);
            }
        }
    }
}

// ---------------------------------------------------------------------------
// x (B,T,E) fp32 + pe[b,e] -> bf16 (B,T,E), with fused per-b LN stats.
__global__ __launch_bounds__(256) void add_pe(const float* __restrict__ x,
                                              const float* __restrict__ pe,
                                              bfu* __restrict__ out,
                                              float* __restrict__ stats) {
    size_t base = (size_t)blockIdx.x * 4096;
    int b = (int)(base >> 20);                 // T_*E_ = 2^20 elems per batch
    float sum = 0.f, sq = 0.f;
    #pragma unroll
    for (int u = 0; u < 4; u++) {
        size_t i = base + u * 1024 + threadIdx.x * 4;
        int e = (int)(i & 511);
        float4 xv = *(const float4*)(x + i);
        float4 pv = *(const float4*)(pe + (b << 9) + e);
        float a0 = xv.x + pv.x, a1 = xv.y + pv.y, a2 = xv.z + pv.z, a3 = xv.w + pv.w;
        ushort4 o = { f2b(a0), f2b(a1), f2b(a2), f2b(a3) };
        *(ushort4*)(out + i) = o;
        sum += a0 + a1 + a2 + a3;
        sq  += a0 * a0 + a1 * a1 + a2 * a2 + a3 * a3;
    }
    #pragma unroll
    for (int off = 32; off > 0; off >>= 1) {
        sum += __shfl_down(sum, off, 64);
        sq  += __shfl_down(sq,  off, 64);
    }
    __shared__ float ss[8];
    int lane = threadIdx.x & 63, wv = threadIdx.x >> 6;
    if (lane == 0) { ss[wv] = sum; ss[4 + wv] = sq; }
    __syncthreads();
    if (threadIdx.x == 0) {
        atomicAdd(&stats[2 * b],     ss[0] + ss[1] + ss[2] + ss[3]);
        atomicAdd(&stats[2 * b + 1], ss[4] + ss[5] + ss[6] + ss[7]);
    }
}

__device__ __forceinline__ float ln_rstd(float sumsq, float mu, float invL) {
    float var = fmaxf(sumsq * invL - mu * mu, 0.f);
    return rsqrtf(var + EPS_);
}

// ---------------------------------------------------------------------------
// Depthwise conv in NHWC (B,T,F), K=7 pad 3, LN fused (per-b stats).
__global__ __launch_bounds__(256) void dwconv_nhwc(const bfu* __restrict__ x,
                                                   const float* __restrict__ stats,
                                                   const float* __restrict__ w,
                                                   const float* __restrict__ bias,
                                                   bfu* __restrict__ out) {
    __shared__ float ws[64 * 57];   // [f-chunk][(f&7)*7 + dt]
    int tid = threadIdx.x;
    int b = blockIdx.z;
    for (int i = tid; i < F_ * KW; i += 256) {
        int f = i / KW, dt = i - f * KW;
        ws[(f >> 3) * 57 + (f & 7) * 7 + dt] = w[i];
    }
    __syncthreads();
    const float invL = 1.0f / (float)(F_ * T_);
    float mu   = stats[2 * b] * invL;
    float rstd = ln_rstd(stats[2 * b + 1], mu, invL);
    int f0 = (tid & 63) * 8;
    int t  = blockIdx.x * 4 + (tid >> 6);
    const bfu* xb = x + (size_t)b * T_ * F_;
    const float* wc_ = &ws[(tid & 63) * 57];
    float acc[8];
    #pragma unroll
    for (int j = 0; j < 8; j++) acc[j] = bias[f0 + j];
    #pragma unroll
    for (int dt = 0; dt < KW; dt++) {
        int tt = t + dt - KW / 2;
        if (tt >= 0 && tt < T_) {
            ushort8v v = *(const ushort8v*)(xb + (size_t)tt * F_ + f0);
            #pragma unroll
            for (int j = 0; j < 8; j++)
                acc[j] += wc_[j * 7 + dt] * ((b2f(v[j]) - mu) * rstd);
        }
    }
    ushort8v o;
    #pragma unroll
    for (int j = 0; j < 8; j++) o[j] = f2b(acc[j]);
    *(ushort8v*)(out + ((size_t)b * T_ + t) * F_ + f0) = o;
}

// ---------------------------------------------------------------------------
// MFMA NT GEMM, 2-phase double-buffered pipeline (counted vmcnt, raw barriers).
// out[r,m] = sum_k A[r,k]*Wb[m,k] + bias[m] (+res). 128x128 tile, BK=32.
// NMAT: number of stacked 512-row weight matrices (QKV=3 in one dispatch).
// Swapped-operand MFMA (bb, a): D row (reg j) spans 4 consecutive m -> packed
// 4-wide C-writes/res-reads. D col = lane&15 -> r. Operand-position mapping
// is the same symmetry attention_mfma already validates.
// GMODE 1: per-block LN stats group g=r0>>11 (per-b). GMODE 2: per 32 rows.
template <typename OutT, int GMODE, int NMAT>
__global__ __launch_bounds__(256, 4) void gemm_mfma(const bfu* __restrict__ A,
                                                    const bfu* __restrict__ Wb,
                                                    const float* __restrict__ bias0,
                                                    const float* __restrict__ bias1,
                                                    const float* __restrict__ bias2,
                                                    const bfu* res,
                                                    OutT* out0, OutT* out1, OutT* out2,
                                                    int out_transpose, float* stats) {
    constexpr int Kd = 512;
    constexpr int NWG = 2048 * NMAT;
    __shared__ bfu As[2][4096];   // 2 x 8 KB, row stride 64 B
    __shared__ bfu Bs[2][4096];
    int id  = blockIdx.x;
    int swz = (id & 7) * (NWG >> 3) + (id >> 3);   // bijective XCD swizzle
    int mt  = swz % (4 * NMAT);                    // m-tile fastest -> A reuse
    int r0  = (swz / (4 * NMAT)) * 128;
    int mat = mt >> 2;
    int m0  = (mt & 3) * 128;
    int tid  = threadIdx.x;
    int wave = tid >> 6, lane = tid & 63;
    int wr = (wave >> 1) * 64, wc = (wave & 1) * 64;
    int lg = lane >> 4,  lr = lane & 15;

    const char* Ab = (const char*)A  + (size_t)r0 * 1024;   // 1024 B per row
    const char* Bb = (const char*)Wb + (size_t)mt * 128 * 1024;
    int rS = (wave << 4) + (lane >> 2);        // staging row within tile
    int kb = (lane & 3) << 4;                  // 16 B chunk within 64 B row
    int ldsoff = wave << 10;                   // wave-uniform LDS base (bytes)

    f32x4 acc[4][4];   // acc[ni][mi]
    #pragma unroll
    for (int ni = 0; ni < 4; ni++)
        #pragma unroll
        for (int mi = 0; mi < 4; mi++)
            acc[ni][mi] = (f32x4){0.f, 0.f, 0.f, 0.f};

    #define STAGE(p, k0)                                                                   \
        do {                                                                               \
            size_t koff_ = (size_t)((k0) << 1);                                            \
            const char* a0_ = Ab + (size_t)rS * 1024 + koff_ + kb;                         \
            const char* b0_ = Bb + (size_t)rS * 1024 + koff_ + kb;                         \
            char* ad_ = (char*)As + (p) * 8192 + ldsoff;                                   \
            char* bd_ = (char*)Bs + (p) * 8192 + ldsoff;                                   \
            __builtin_amdgcn_global_load_lds((gp1_t)a0_,           (lp3_t)ad_,          16, 0, 0); \
            __builtin_amdgcn_global_load_lds((gp1_t)(a0_ + 65536), (lp3_t)(ad_ + 4096), 16, 0, 0); \
            __builtin_amdgcn_global_load_lds((gp1_t)b0_,           (lp3_t)bd_,          16, 0, 0); \
            __builtin_amdgcn_global_load_lds((gp1_t)(b0_ + 65536), (lp3_t)(bd_ + 4096), 16, 0, 0); \
        } while (0)

    STAGE(0, 0);
    #pragma unroll 2
    for (int it = 0; it < 16; ++it) {
        int cur = it & 1;
        if (it < 15) {
            STAGE(cur ^ 1, (it + 1) * 32);
            asm volatile("s_waitcnt vmcnt(4)" ::: "memory");   // cur tile landed, next in flight
        } else {
            asm volatile("s_waitcnt vmcnt(0)" ::: "memory");
        }
        __builtin_amdgcn_sched_barrier(0);
        __builtin_amdgcn_s_barrier();
        __builtin_amdgcn_sched_barrier(0);
        const bfu* Ap = &As[cur][(wr + lr) * 32 + lg * 8];
        const bfu* Bp = &Bs[cur][(wc + lr) * 32 + lg * 8];
        short8v a[4], bb[4];
        #pragma unroll
        for (int mi = 0; mi < 4; mi++) a[mi]  = *(const short8v*)(Ap + mi * 512);
        #pragma unroll
        for (int ni = 0; ni < 4; ni++) bb[ni] = *(const short8v*)(Bp + ni * 512);
        #pragma unroll
        for (int ni = 0; ni < 4; ni++)
            #pragma unroll
            for (int mi = 0; mi < 4; mi++)
                acc[ni][mi] = __builtin_amdgcn_mfma_f32_16x16x32_bf16(bb[ni], a[mi], acc[ni][mi], 0, 0, 0);
        asm volatile("s_waitcnt lgkmcnt(0)" ::: "memory");     // reads done before others re-stage
        __builtin_amdgcn_sched_barrier(0);
        __builtin_amdgcn_s_barrier();
    }
    #undef STAGE

    const float* bias = (NMAT == 1 || mat == 0) ? bias0 : (mat == 1 ? bias1 : bias2);
    OutT*        outb = (NMAT == 1 || mat == 0) ? out0  : (mat == 1 ? out1  : out2);

    float sAcc0 = 0.f, sAcc1 = 0.f, qAcc0 = 0.f, qAcc1 = 0.f;
    #pragma unroll
    for (int mi = 0; mi < 4; mi++) {
        int r = r0 + wr + mi * 16 + lr;
        #pragma unroll
        for (int ni = 0; ni < 4; ni++) {
            int mo = m0 + wc + ni * 16 + lg * 4;   // 4-aligned column within matrix
            float4 bv = *(const float4*)(bias + mo);
            float v0 = acc[ni][mi][0] + bv.x;
            float v1 = acc[ni][mi][1] + bv.y;
            float v2 = acc[ni][mi][2] + bv.z;
            float v3 = acc[ni][mi][3] + bv.w;
            if (res) {
                ushort4 rv = *(const ushort4*)(res + (size_t)r * 512 + mo);
                v0 += b2f(rv.x); v1 += b2f(rv.y); v2 += b2f(rv.z); v3 += b2f(rv.w);
            }
            if (GMODE) {
                float s = v0 + v1 + v2 + v3;
                float q = v0 * v0 + v1 * v1 + v2 * v2 + v3 * v3;
                if (mi < 2) { sAcc0 += s; qAcc0 += q; }
                else        { sAcc1 += s; qAcc1 += q; }
            }
            if (!out_transpose) {
                st4(outb, (size_t)r * 512 + mo, v0, v1, v2, v3);
            } else {
                int t = r >> 5, bb2 = r & 31;
                st4(outb, ((size_t)bb2 * T_ + t) * 512 + mo, v0, v1, v2, v3);
            }
        }
    }
    if (GMODE == 1) {
        float s = sAcc0 + sAcc1, q = qAcc0 + qAcc1;
        #pragma unroll
        for (int off = 32; off > 0; off >>= 1) {
            s += __shfl_down(s, off, 64);
            q += __shfl_down(q, off, 64);
        }
        if (lane == 0) {
            int g = r0 >> 11;
            atomicAdd(&stats[2 * g], s);
            atomicAdd(&stats[2 * g + 1], q);
        }
    } else if (GMODE == 2) {
        #pragma unroll
        for (int off = 32; off > 0; off >>= 1) {
            sAcc0 += __shfl_down(sAcc0, off, 64); qAcc0 += __shfl_down(qAcc0, off, 64);
            sAcc1 += __shfl_down(sAcc1, off, 64); qAcc1 += __shfl_down(qAcc1, off, 64);
        }
        if (lane == 0) {
            int g0 = (r0 >> 5) + (wr >> 5);   // wave's first 32-row group
            atomicAdd(&stats[2 * g0],     sAcc0);
            atomicAdd(&stats[2 * g0 + 1], qAcc0);
            atomicAdd(&stats[2 * g0 + 2], sAcc1);
            atomicAdd(&stats[2 * g0 + 3], qAcc1);
        }
    }
}

// ---------------------------------------------------------------------------
// (B,T,F) -> (T,B,F): xa = raw copy, yln = LN-applied (per-b stats).
__global__ __launch_bounds__(256) void bt2tb_ln(const bfu* __restrict__ x,
                                                const float* __restrict__ stats,
                                                bfu* __restrict__ xa,
                                                bfu* __restrict__ yln) {
    size_t i = ((size_t)blockIdx.x * 256 + threadIdx.x) * 8;
    int f = (int)(i & 511);
    size_t bt = i >> 9;
    int t = (int)(bt & 2047);
    int b = (int)(bt >> 11);
    const float invL = 1.0f / (float)(F_ * T_);
    float mu   = stats[2 * b] * invL;
    float rstd = ln_rstd(stats[2 * b + 1], mu, invL);
    ushort8v v = *(const ushort8v*)(x + i);
    size_t dst = (((size_t)t * B_ + b) << 9) + f;
    *(ushort8v*)(xa + dst) = v;
    ushort8v o;
    #pragma unroll
    for (int j = 0; j < 8; j++) o[j] = f2b((b2f(v[j]) - mu) * rstd);
    *(ushort8v*)(yln + dst) = o;
}

// LN apply over contiguous groups of (1<<shift) elems.
__global__ __launch_bounds__(256) void ln_apply(const bfu* __restrict__ x,
                                                const float* __restrict__ stats,
                                                bfu* __restrict__ out,
                                                float invL, int shift) {
    size_t i = ((size_t)blockIdx.x * 256 + threadIdx.x) * 8;
    int g = (int)(i >> shift);
    float mu   = stats[2 * g] * invL;
    float rstd = ln_rstd(stats[2 * g + 1], mu, invL);
    ushort8v v = *(const ushort8v*)(x + i);
    ushort8v o;
    #pragma unroll
    for (int j = 0; j < 8; j++) o[j] = f2b((b2f(v[j]) - mu) * rstd);
    *(ushort8v*)(out + i) = o;
}

// ---------------------------------------------------------------------------
// MFMA attention over the batch axis. One wave per (t,h); 4 waves/block.
__global__ __launch_bounds__(256) void attention_mfma(const bfu* __restrict__ Q,
                                                      const bfu* __restrict__ K,
                                                      const bfu* __restrict__ V,
                                                      bfu* __restrict__ O) {
    __shared__ bfu vt[4][64 * 36];   // per-wave V^T [d][c], padded stride 36
    int tid = threadIdx.x;
    int wave = tid >> 6, lane = tid & 63;
    int wid = blockIdx.x * 4 + wave;
    int t = wid >> 3, h = wid & 7;
    int lh = lane >> 5, lm = lane & 31;
    size_t base = (size_t)t * (B_ * F_) + (size_t)h * 64;

    short8v qf[4], kf[4];
    const bfu* qrow = Q + base + (size_t)lm * F_ + lh * 8;
    const bfu* krow = K + base + (size_t)lm * F_ + lh * 8;
    #pragma unroll
    for (int s = 0; s < 4; s++) {
        qf[s] = *(const short8v*)(qrow + s * 16);
        kf[s] = *(const short8v*)(krow + s * 16);
    }
    bfu* vt_w = vt[wave];
    {
        int c = lane >> 1, d0 = (lane & 1) * 32;
        const bfu* vrow = V + base + (size_t)c * F_ + d0;
        #pragma unroll
        for (int j = 0; j < 4; j++) {
            ushort8v vv = *(const ushort8v*)(vrow + j * 8);
            #pragma unroll
            for (int e = 0; e < 8; e++)
                vt_w[(d0 + j * 8 + e) * 36 + c] = vv[e];
        }
    }
    f32x16 st;
    #pragma unroll
    for (int r = 0; r < 16; r++) st[r] = 0.f;
    #pragma unroll
    for (int s = 0; s < 4; s++)
        st = __builtin_amdgcn_mfma_f32_32x32x16_bf16(kf[s], qf[s], st, 0, 0, 0);

    float p[16];
    float mx = -1e30f;
    #pragma unroll
    for (int r = 0; r < 16; r++) { p[r] = st[r] * 0.125f; mx = fmaxf(mx, p[r]); }
    mx = fmaxf(mx, __shfl_xor(mx, 32, 64));
    float sum = 0.f;
    #pragma unroll
    for (int r = 0; r < 16; r++) { p[r] = expf(p[r] - mx); sum += p[r]; }
    sum += __shfl_xor(sum, 32, 64);
    float inv = 1.0f / sum;
    short8v pa[2];
    #pragma unroll
    for (int j = 0; j < 8; j++) {
        pa[0][j] = (short)f2b(p[j] * inv);
        pa[1][j] = (short)f2b(p[8 + j] * inv);
    }
    f32x16 oacc[2];
    #pragma unroll
    for (int dt = 0; dt < 2; dt++)
        #pragma unroll
        for (int r = 0; r < 16; r++) oacc[dt][r] = 0.f;
    #pragma unroll
    for (int dt = 0; dt < 2; dt++) {
        const bfu* vr = vt_w + (dt * 32 + lm) * 36 + lh * 4;
        #pragma unroll
        for (int kh = 0; kh < 2; kh++) {
            short4v b0 = *(const short4v*)(vr + kh * 16);
            short4v b1 = *(const short4v*)(vr + kh * 16 + 8);
            short8v bf;
            #pragma unroll
            for (int e = 0; e < 4; e++) { bf[e] = b0[e]; bf[4 + e] = b1[e]; }
            oacc[dt] = __builtin_amdgcn_mfma_f32_32x32x16_bf16(pa[kh], bf, oacc[dt], 0, 0, 0);
        }
    }
    bfu* orow = O + base + lm;
    #pragma unroll
    for (int dt = 0; dt < 2; dt++)
        #pragma unroll
        for (int r = 0; r < 16; r++) {
            int b = (r & 3) + 8 * (r >> 2) + 4 * lh;
            orow[(size_t)b * F_ + dt * 32] = f2b(oacc[dt][r]);
        }
}

// ---------------------------------------------------------------------------
extern "C" void kernel_launch(void* const* d_in, const int* in_sizes, int n_in,
                              void* d_out, int out_size, void* d_ws, size_t ws_size,
                              hipStream_t stream) {
    const float* x     = (const float*)d_in[0];
    const float* dw1_w = (const float*)d_in[1];
    const float* dw1_b = (const float*)d_in[2];
    const float* pw1_w = (const float*)d_in[3];
    const float* pw1_b = (const float*)d_in[4];
    const float* dw2_w = (const float*)d_in[5];
    const float* dw2_b = (const float*)d_in[6];
    const float* pw2_w = (const float*)d_in[7];
    const float* pw2_b = (const float*)d_in[8];
    const float* wq = (const float*)d_in[9];   const float* bq = (const float*)d_in[10];
    const float* wk = (const float*)d_in[11];  const float* bk = (const float*)d_in[12];
    const float* wv = (const float*)d_in[13];  const float* bv = (const float*)d_in[14];
    const float* wp = (const float*)d_in[15];  const float* bp = (const float*)d_in[16];
    const float* ffw = (const float*)d_in[17]; const float* ffb = (const float*)d_in[18];
    float* out = (float*)d_out;

    const size_t SZ = (size_t)B_ * F_ * T_;   // 33,554,432 elems (64 MB bf16)
    const size_t WN = (size_t)F_ * F_;

    // Workspace: [stats 32KB][pe 64KB][7 bf16 weights 3.5MB] ... big bufs @ +4MB
    float* stats = (float*)d_ws;              // 8192 fp32 total stat space
    float* stA = stats;                       // add_pe   (per-b, 64 used)
    float* st1 = stats + 128;                 // gemm pw1 (per-b)
    float* st2 = stats + 256;                 // gemm pw2 it0
    float* st3 = stats + 384;                 // gemm pw2 it1
    float* st4 = stats + 512;                 // gemm pw2 it2
    float* stT = stats + 1024;                // gemm wp  (per-t, 4096 used)
    float* peTab = stats + 8192;              // 16384 fp32
    bfu*   wBuf  = (bfu*)(peTab + 16384);
    bfu* wb_pw1 = wBuf + 0 * WN;
    bfu* wb_pw2 = wBuf + 1 * WN;
    bfu* wb_q   = wBuf + 2 * WN;              // q,k,v contiguous => NMAT=3 stack
    bfu* wb_p   = wBuf + 5 * WN;
    bfu* wb_ff  = wBuf + 6 * WN;
    bfu* bufX = (bfu*)d_ws + (1 << 21);       // +4 MB: act (B,T,F); later Q
    bfu* bufC = bufX + SZ;                    // dwconv scratch; later xa (T,B,F)
    bfu* bufY = bufC + SZ;                    // yln (T,B,F); later attn O
    bfu* bufK = bufY + SZ;
    bfu* bufV = bufK + SZ;

    zero_kernel<<<32, 256, 0, stream>>>(stats, 8192);
    prep<<<1808, 256, 0, stream>>>(pw1_w, pw2_w, wq, wk, wv, wp, ffw, wBuf, peTab);
    add_pe<<<8192, 256, 0, stream>>>(x, peTab, bufX, stA);

    // conv1: x = pw1(dw1(ln(x0)))   [all in (B,T,F)]
    dwconv_nhwc<<<dim3(T_ / 4, 1, B_), 256, 0, stream>>>(bufX, stA, dw1_w, dw1_b, bufC);
    gemm_mfma<bfu, 1, 1><<<2048, 256, 0, stream>>>(bufC, wb_pw1, pw1_b, pw1_b, pw1_b,
                                                   nullptr, bufX, bufX, bufX, 0, st1);

    // conv loop (shared dw2/pw2 weights), residual + stats fused into gemm
    float* sts[3] = { st2, st3, st4 };
    for (int it = 0; it < 3; ++it) {
        float* sin_ = (it == 0) ? st1 : sts[it - 1];
        dwconv_nhwc<<<dim3(T_ / 4, 1, B_), 256, 0, stream>>>(bufX, sin_, dw2_w, dw2_b, bufC);
        gemm_mfma<bfu, 1, 1><<<2048, 256, 0, stream>>>(bufC, wb_pw2, pw2_b, pw2_b, pw2_b,
                                                       bufX, bufX, bufX, bufX, 0, sts[it]);
    }

    // to (T,B,F): xa = x (bufC), yln = ln(x) (bufY)
    bt2tb_ln<<<16384, 256, 0, stream>>>(bufX, st4, bufC, bufY);

    // QKV in ONE dispatch (weights stacked at wb_q): Q->bufX, K->bufK, V->bufV
    gemm_mfma<bfu, 0, 3><<<6144, 256, 0, stream>>>(bufY, wb_q, bq, bk, bv,
                                                   nullptr, bufX, bufK, bufV, 0, nullptr);

    // attention across batch axis (yln dead -> bufY holds O)
    attention_mfma<<<4096, 256, 0, stream>>>(bufX, bufK, bufV, bufY);

    // output projection + residual (xa in bufC) + per-t stats: xnew -> bufK
    gemm_mfma<bfu, 2, 1><<<2048, 256, 0, stream>>>(bufY, wb_p, bp, bp, bp,
                                                   bufC, bufK, bufK, bufK, 0, stT);

    // final LN per t over (B,F) = 16384 contiguous elems per group
    ln_apply<<<16384, 256, 0, stream>>>(bufK, stT, bufX, 1.0f / (float)(B_ * F_), 14);

    // FF gemm: A = ln(xnew), residual = xnew, fp32 (B,T,F) transposed output
    gemm_mfma<float, 0, 1><<<2048, 256, 0, stream>>>(bufX, wb_ff, ffb, ffb, ffb,
                                                     bufK, out, out, out, 1, nullptr);
}